// Round 4
// baseline (93.843 us; speedup 1.0000x reference)
//
#include <hip/hip_runtime.h>

typedef float f2 __attribute__((ext_vector_type(2)));
typedef float f4 __attribute__((ext_vector_type(4)));
typedef _Float16 h4 __attribute__((ext_vector_type(4)));

constexpr int Hh = 224, Ww = 224, Bb = 8, Kc = 4, RAD = 5;

// 256 threads = 32x8; each thread computes 2 vertically-adjacent pixels -> 32x16 tile
constexpr int TX = 32;
constexpr int TILEH = 16;
constexpr int SW = TX + 2 * RAD;      // 42
constexpr int SH = TILEH + 2 * RAD;   // 26
constexpr int SSTR = SW + 1;          // 43 (odd -> conflict-free; col 42 = pad column)
constexpr int GXD = Ww / TX;          // 7
constexpr int GYD = Hh / TILEH;       // 14
constexpr int PB = GXD * GYD;         // 98 blocks per batch image

constexpr float LOG2E = 1.44269504f;
constexpr float KI = -0.01f * LOG2E;         // intensity coeff (pre-scaled for exp2)
constexpr float DSC = -0.0625f * LOG2E;      // dist coeff     (pre-scaled for exp2)
// d^2 per kernel offset; index 11 is dx=+6 (outside the 11-wide window).
// D2[11]=1e5 -> compile-time base ~ -9000 -> exp2 underflows to exactly 0,
// killing the spurious 122nd tap that D2[11]=0 used to admit for tx<31.
constexpr float D2[12] = {25.f,16.f,9.f,4.f,1.f,0.f,1.f,4.f,9.f,16.f,25.f,1e5f};

static __device__ inline f4 splat4(float x) { return (f4){x, x, x, x}; }

__global__ __launch_bounds__(256, 3) void ncut_main(const float* __restrict__ images,
                                                    const float* __restrict__ labels,
                                                    float* __restrict__ acc) {
    __shared__ float simg[SH * SSTR];
    __shared__ h4    slab[SH * SSTR];     // labels as f16x4: halves the dominant LDS stream
    __shared__ float red[4][8];

    const int b   = blockIdx.z;
    const int x0  = blockIdx.x * TX;
    const int y0  = blockIdx.y * TILEH;
    const int tid = threadIdx.x;

    const float* imgb = images + (size_t)b * (Hh * Ww);
    const float* labb = labels + (size_t)b * (Kc * Hh * Ww);

    // Stage tile + halo (incl. the stride-pad column as OOB).
    // OOB: img = 1e19 -> single-exp weight underflows to exactly 0; labels = 0.
    for (int idx = tid; idx < SH * SSTR; idx += 256) {
        const int lx = idx % SSTR, ly = idx / SSTR;
        const int gx = x0 - RAD + lx, gy = y0 - RAD + ly;
        float iv = 1e19f;
        h4 lv = (h4){(_Float16)0.f, (_Float16)0.f, (_Float16)0.f, (_Float16)0.f};
        if (lx < SW && gx >= 0 && gx < Ww && gy >= 0 && gy < Hh) {
            const int g = gy * Ww + gx;
            iv = imgb[g] * 255.0f;
            lv = (h4){(_Float16)labb[g], (_Float16)labb[Hh * Ww + g],
                      (_Float16)labb[2 * Hh * Ww + g], (_Float16)labb[3 * Hh * Ww + g]};
        }
        simg[idx] = iv;
        slab[idx] = lv;
    }
    __syncthreads();

    const int tx = tid & 31;
    const int ty = tid >> 5;      // 0..7
    const int r0 = 2 * ty;        // top LDS row of this thread's 12-row window

    const float c0 = simg[(r0 + RAD) * SSTR + tx + RAD];
    const float c1 = simg[(r0 + RAD + 1) * SSTR + tx + RAD];

    f4 num0 = splat4(0.f), num1 = splat4(0.f);
    f2 den0 = (f2){0.f, 0.f}, den1 = (f2){0.f, 0.f};

    // 12 rows: row dr serves center0 (dy=dr, dr<11) and center1 (dy=dr-1, dr>=1)
#pragma unroll
    for (int dr = 0; dr < 12; ++dr) {
        const int rowoff = (r0 + dr) * SSTR + tx;
#pragma unroll
        for (int i = 0; i < 6; ++i) {
            const f2 v  = (f2){simg[rowoff + 2 * i], simg[rowoff + 2 * i + 1]};
            const f4 p0 = __builtin_convertvector(slab[rowoff + 2 * i], f4);
            const f4 p1 = __builtin_convertvector(slab[rowoff + 2 * i + 1], f4);
            if (dr < 11) {
                const f2 base = (f2){(D2[2 * i] + D2[dr]) * DSC,
                                     (D2[2 * i + 1] + D2[dr]) * DSC};
                const f2 d = v - c0;
                const f2 a = __builtin_elementwise_fma(d * KI, d, base);
                const float e0 = __builtin_amdgcn_exp2f(a.x);
                const float e1 = __builtin_amdgcn_exp2f(a.y);
                den0 += (f2){e0, e1};
                num0 = __builtin_elementwise_fma(splat4(e0), p0, num0);
                num0 = __builtin_elementwise_fma(splat4(e1), p1, num0);
            }
            if (dr >= 1) {
                const f2 base = (f2){(D2[2 * i] + D2[dr - 1]) * DSC,
                                     (D2[2 * i + 1] + D2[dr - 1]) * DSC};
                const f2 d = v - c1;
                const f2 a = __builtin_elementwise_fma(d * KI, d, base);
                const float e0 = __builtin_amdgcn_exp2f(a.x);
                const float e1 = __builtin_amdgcn_exp2f(a.y);
                den1 += (f2){e0, e1};
                num1 = __builtin_elementwise_fma(splat4(e0), p0, num1);
                num1 = __builtin_elementwise_fma(splat4(e1), p1, num1);
            }
        }
    }

    const f4 pc0 = __builtin_convertvector(slab[(r0 + RAD) * SSTR + tx + RAD], f4);
    const f4 pc1 = __builtin_convertvector(slab[(r0 + RAD + 1) * SSTR + tx + RAD], f4);
    const float dn0 = den0.x + den0.y;
    const float dn1 = den1.x + den1.y;

    const f4 numv = pc0 * num0 + pc1 * num1;                 // per-class sum p_f * num
    const f4 denv = pc0 * dn0 + pc1 * dn1;                   // per-class sum p_f * den

    float vals[8] = {numv.x, numv.y, numv.z, numv.w, denv.x, denv.y, denv.z, denv.w};

#pragma unroll
    for (int i = 0; i < 8; ++i) {
        float v = vals[i];
#pragma unroll
        for (int off = 32; off > 0; off >>= 1) v += __shfl_down(v, off, 64);
        vals[i] = v;
    }

    const int wave = tid >> 6, lane = tid & 63;
    if (lane == 0) {
#pragma unroll
        for (int i = 0; i < 8; ++i) red[wave][i] = vals[i];
    }
    __syncthreads();

    if (tid < 8) {
        const int gid = blockIdx.x + GXD * blockIdx.y + GXD * GYD * blockIdx.z;
        acc[gid * 8 + tid] = red[0][tid] + red[1][tid] + red[2][tid] + red[3][tid];
    }
}

__global__ void ncut_final(const float* __restrict__ acc, float* __restrict__ out) {
    __shared__ float red[4][64];
    const int t = threadIdx.x;           // 0..255
    const int combo = t & 63;
    const int chunk = t >> 6;            // 0..3
    const int k = combo & 3, b = (combo >> 2) & 7;
    const int part = combo >> 5;         // 0 = num, 1 = den
    float s = 0.f;
    for (int j = chunk; j < PB; j += 4)
        s += acc[(b * PB + j) * 8 + k + 4 * part];
    red[chunk][combo] = s;
    __syncthreads();
    if (t < 64) {
        float v = red[0][t] + red[1][t] + red[2][t] + red[3][t];
        const float den = __shfl(v, (t + 32) & 63, 64);
        float r = (t < 32) ? fabsf(v / den) : 0.f;
#pragma unroll
        for (int off = 32; off > 0; off >>= 1) r += __shfl_down(r, off, 64);
        if (t == 0) out[0] = (float)Kc - r * (1.0f / (float)Bb);
    }
}

extern "C" void kernel_launch(void* const* d_in, const int* in_sizes, int n_in,
                              void* d_out, int out_size, void* d_ws, size_t ws_size,
                              hipStream_t stream) {
    const float* images = (const float*)d_in[0];
    const float* labels = (const float*)d_in[1];
    float* out = (float*)d_out;
    float* acc = (float*)d_ws;  // PB*Bb blocks * 8 partials, fully overwritten each launch

    dim3 grid(GXD, GYD, Bb);    // 7 x 14 x 8
    ncut_main<<<grid, 256, 0, stream>>>(images, labels, acc);
    ncut_final<<<1, 256, 0, stream>>>(acc, out);
}

// Round 6
// 89.496 us; speedup vs baseline: 1.0486x; 1.0486x over previous
//
#include <hip/hip_runtime.h>
#include <type_traits>

typedef float f2 __attribute__((ext_vector_type(2)));
typedef float f4 __attribute__((ext_vector_type(4)));

constexpr int Hh = 224, Ww = 224, Bb = 8, Kc = 4, RAD = 5;

// 512 threads = 2 groups x (32x8); 32x16 tile, 2 px/thread, stencil ROWS split
// across the two groups (group 0: dr 0..5, group 1: dr 6..11). Same total work
// as the 256-thread version, 2x the waves -> 6.1 waves/SIMD for latency hiding.
constexpr int TX = 32;
constexpr int TILEH = 16;
constexpr int NTHR = 512;
constexpr int SW = TX + 2 * RAD;      // 42
constexpr int SH = TILEH + 2 * RAD;   // 26
constexpr int SSTR = SW + 1;          // 43
constexpr int GXD = Ww / TX;          // 7
constexpr int GYD = Hh / TILEH;       // 14
constexpr int PB = GXD * GYD;         // 98 blocks per batch image

constexpr float LOG2E = 1.44269504f;
constexpr float KI = -0.01f * LOG2E;         // intensity coeff (pre-scaled for exp2)
constexpr float DSC = -0.0625f * LOG2E;      // dist coeff     (pre-scaled for exp2)
// d^2 per kernel offset; index 11 is dx=+6 (outside the 11-wide window).
// D2[11]=1e5 -> compile-time base ~ -9000 -> exp2 underflows to exactly 0.
constexpr float D2[12] = {25.f,16.f,9.f,4.f,1.f,0.f,1.f,4.f,9.f,16.f,25.f,1e5f};

static __device__ inline f4 splat4(float x) { return (f4){x, x, x, x}; }

__global__ __launch_bounds__(NTHR, 6) void ncut_main(const float* __restrict__ images,
                                                     const float* __restrict__ labels,
                                                     float* __restrict__ acc) {
    __shared__ float simg[SH * SSTR];
    __shared__ f4    slab[SH * SSTR];
    __shared__ float red[8][8];

    const int b   = blockIdx.z;
    const int x0  = blockIdx.x * TX;
    const int y0  = blockIdx.y * TILEH;
    const int tid = threadIdx.x;

    const float* imgb = images + (size_t)b * (Hh * Ww);
    const float* labb = labels + (size_t)b * (Kc * Hh * Ww);

    // Stage tile + halo (incl. the stride-pad column as OOB).
    // OOB: img = 1e19 -> single-exp weight underflows to exactly 0; labels = 0.
    for (int idx = tid; idx < SH * SSTR; idx += NTHR) {
        const int lx = idx % SSTR, ly = idx / SSTR;
        const int gx = x0 - RAD + lx, gy = y0 - RAD + ly;
        float iv = 1e19f;
        f4 lv = (f4){0.f, 0.f, 0.f, 0.f};
        if (lx < SW && gx >= 0 && gx < Ww && gy >= 0 && gy < Hh) {
            const int g = gy * Ww + gx;
            iv = imgb[g] * 255.0f;
            lv = (f4){labb[g], labb[Hh * Ww + g], labb[2 * Hh * Ww + g], labb[3 * Hh * Ww + g]};
        }
        simg[idx] = iv;
        slab[idx] = lv;
    }
    __syncthreads();

    const int tx  = tid & 31;
    const int ty  = (tid >> 5) & 7;   // 0..7 -> which pixel-pair row
    const int grp = tid >> 8;         // 0..1 -> which half of the stencil rows
    const int r0  = 2 * ty;           // top LDS row of this pixel-pair's 12-row window

    const float c0 = simg[(r0 + RAD) * SSTR + tx + RAD];
    const float c1 = simg[(r0 + RAD + 1) * SSTR + tx + RAD];

    f4 num0 = splat4(0.f), num1 = splat4(0.f);
    f2 den0 = (f2){0.f, 0.f}, den1 = (f2){0.f, 0.f};

    // Row dr serves center0 (dy=dr-5, active dr<11) and center1 (dy=dr-6, active dr>=1).
    // Group G handles dr = 6G .. 6G+5; guards fold at compile time per unrolled iter.
    auto body = [&](auto GC) {
        constexpr int G = decltype(GC)::value;
#pragma unroll
        for (int d = 0; d < 6; ++d) {
            const int dr = 6 * G + d;                 // compile-time after unroll
            const int rowoff = (r0 + dr) * SSTR + tx;
#pragma unroll
            for (int i = 0; i < 6; ++i) {
                const f2 v  = (f2){simg[rowoff + 2 * i], simg[rowoff + 2 * i + 1]};
                const f4 p0 = slab[rowoff + 2 * i];
                const f4 p1 = slab[rowoff + 2 * i + 1];
                if (dr < 11) {
                    const f2 base = (f2){(D2[2 * i] + D2[dr]) * DSC,
                                         (D2[2 * i + 1] + D2[dr]) * DSC};
                    const f2 dd = v - c0;
                    const f2 a = __builtin_elementwise_fma(dd * KI, dd, base);
                    const float e0 = __builtin_amdgcn_exp2f(a.x);
                    const float e1 = __builtin_amdgcn_exp2f(a.y);
                    den0 += (f2){e0, e1};
                    num0 = __builtin_elementwise_fma(splat4(e0), p0, num0);
                    num0 = __builtin_elementwise_fma(splat4(e1), p1, num0);
                }
                if (dr >= 1) {
                    const f2 base = (f2){(D2[2 * i] + D2[dr - 1]) * DSC,
                                         (D2[2 * i + 1] + D2[dr - 1]) * DSC};
                    const f2 dd = v - c1;
                    const f2 a = __builtin_elementwise_fma(dd * KI, dd, base);
                    const float e0 = __builtin_amdgcn_exp2f(a.x);
                    const float e1 = __builtin_amdgcn_exp2f(a.y);
                    den1 += (f2){e0, e1};
                    num1 = __builtin_elementwise_fma(splat4(e0), p0, num1);
                    num1 = __builtin_elementwise_fma(splat4(e1), p1, num1);
                }
            }
        }
    };
    if (grp == 0) body(std::integral_constant<int, 0>{});
    else          body(std::integral_constant<int, 1>{});

    // per-class sums of p_f * num and p_f * den over this thread's 2 pixels
    // (partial within this group's stencil rows; cross-group merge happens in red[][])
    const f4 pc0 = slab[(r0 + RAD) * SSTR + tx + RAD];
    const f4 pc1 = slab[(r0 + RAD + 1) * SSTR + tx + RAD];
    const float dn0 = den0.x + den0.y;
    const float dn1 = den1.x + den1.y;

    const f4 numv = pc0 * num0 + pc1 * num1;
    const f4 denv = pc0 * dn0 + pc1 * dn1;

    float vals[8] = {numv.x, numv.y, numv.z, numv.w, denv.x, denv.y, denv.z, denv.w};

#pragma unroll
    for (int i = 0; i < 8; ++i) {
        float v = vals[i];
#pragma unroll
        for (int off = 32; off > 0; off >>= 1) v += __shfl_down(v, off, 64);
        vals[i] = v;
    }

    const int wave = tid >> 6, lane = tid & 63;   // 8 waves
    if (lane == 0) {
#pragma unroll
        for (int i = 0; i < 8; ++i) red[wave][i] = vals[i];
    }
    __syncthreads();

    if (tid < 8) {
        const int gid = blockIdx.x + GXD * blockIdx.y + GXD * GYD * blockIdx.z;
        float s = 0.f;
#pragma unroll
        for (int w = 0; w < 8; ++w) s += red[w][tid];
        acc[gid * 8 + tid] = s;
    }
}

__global__ void ncut_final(const float* __restrict__ acc, float* __restrict__ out) {
    __shared__ float red[4][64];
    const int t = threadIdx.x;           // 0..255
    const int combo = t & 63;
    const int chunk = t >> 6;            // 0..3
    const int k = combo & 3, b = (combo >> 2) & 7;
    const int part = combo >> 5;         // 0 = num, 1 = den
    float s = 0.f;
    for (int j = chunk; j < PB; j += 4)
        s += acc[(b * PB + j) * 8 + k + 4 * part];
    red[chunk][combo] = s;
    __syncthreads();
    if (t < 64) {
        float v = red[0][t] + red[1][t] + red[2][t] + red[3][t];
        const float den = __shfl(v, (t + 32) & 63, 64);
        float r = (t < 32) ? fabsf(v / den) : 0.f;
#pragma unroll
        for (int off = 32; off > 0; off >>= 1) r += __shfl_down(r, off, 64);
        if (t == 0) out[0] = (float)Kc - r * (1.0f / (float)Bb);
    }
}

extern "C" void kernel_launch(void* const* d_in, const int* in_sizes, int n_in,
                              void* d_out, int out_size, void* d_ws, size_t ws_size,
                              hipStream_t stream) {
    const float* images = (const float*)d_in[0];
    const float* labels = (const float*)d_in[1];
    float* out = (float*)d_out;
    float* acc = (float*)d_ws;  // PB*Bb blocks * 8 partials, fully overwritten each launch

    dim3 grid(GXD, GYD, Bb);    // 7 x 14 x 8
    ncut_main<<<grid, NTHR, 0, stream>>>(images, labels, acc);
    ncut_final<<<1, 256, 0, stream>>>(acc, out);
}

// Round 7
// 85.674 us; speedup vs baseline: 1.0953x; 1.0446x over previous
//
#include <hip/hip_runtime.h>
#include <type_traits>

typedef float f2 __attribute__((ext_vector_type(2)));
typedef float f4 __attribute__((ext_vector_type(4)));
typedef _Float16 h2t __attribute__((ext_vector_type(2)));

constexpr int Hh = 224, Ww = 224, Bb = 8, Kc = 4, RAD = 5;

// 512 threads = 2 row-groups x (32 tx x 8 ty); each thread owns 4 vertically-adjacent
// pixels -> 32x32 tile. The 14 stencil rows per pixel-quad are split across the two
// groups (group 0: dr 0..6, group 1: dr 7..13) -> 3.06 waves/SIMD (R3's proven level).
// PPT=4 amortizes each LDS tap-read over ~2.9 centers (42 reads/px vs 72 at PPT=2).
constexpr int TX = 32;
constexpr int TILEH = 32;
constexpr int NTHR = 512;
constexpr int SW = TX + 2 * RAD;      // 42
constexpr int SH = TILEH + 2 * RAD;   // 42
constexpr int SSTR = SW + 1;          // 43 (odd; col 42 = pad column)
constexpr int GXD = Ww / TX;          // 7
constexpr int GYD = Hh / TILEH;       // 7
constexpr int PB = GXD * GYD;         // 49 blocks per batch image

constexpr float LOG2E = 1.44269504f;
constexpr float KI = -0.01f * LOG2E;         // intensity coeff (pre-scaled for exp2)
constexpr float DSC = -0.0625f * LOG2E;      // dist coeff     (pre-scaled for exp2)
// d^2 per kernel offset; index 11 is dx=+6 (outside the 11-wide window).
// D2[11]=1e5 -> compile-time base ~ -9000 -> exp2 underflows to exactly 0.
constexpr float D2[12] = {25.f,16.f,9.f,4.f,1.f,0.f,1.f,4.f,9.f,16.f,25.f,1e5f};

static __device__ inline f4 splat4(float x) { return (f4){x, x, x, x}; }

// f16 pack/unpack that CANNOT degrade to ds_read_u16: the halves live inside an
// f32-typed vector in LDS; conversion is pure VALU (v_cvt_pkrtz / v_cvt_f32_f16).
static __device__ inline float pack2(float a, float b) {
    return __builtin_bit_cast(float, __builtin_amdgcn_cvt_pkrtz(a, b));
}
static __device__ inline f4 unpack4(float y, float z) {
    const h2t a = __builtin_bit_cast(h2t, y);
    const h2t b = __builtin_bit_cast(h2t, z);
    return (f4){(float)a.x, (float)a.y, (float)b.x, (float)b.y};
}

__global__ __launch_bounds__(NTHR, 4) void ncut_main(const float* __restrict__ images,
                                                     const float* __restrict__ labels,
                                                     float* __restrict__ acc) {
    // fused tap record: {img*255 (f32), labels k0,k1 (f16x2), labels k2,k3 (f16x2), pad}
    // -> exactly ONE ds_read_b128 delivers everything for a tap.
    __shared__ f4 stap[SH * SSTR];               // 42*43*16 = 28.9 KB
    __shared__ float red[8][8];

    const int b   = blockIdx.z;
    const int x0  = blockIdx.x * TX;
    const int y0  = blockIdx.y * TILEH;
    const int tid = threadIdx.x;

    const float* imgb = images + (size_t)b * (Hh * Ww);
    const float* labb = labels + (size_t)b * (Kc * Hh * Ww);

    // Stage tile + halo (incl. the stride-pad column as OOB).
    // OOB: img = 1e19 -> weight underflows to exactly 0; labels = 0.
    for (int idx = tid; idx < SH * SSTR; idx += NTHR) {
        const int lx = idx % SSTR, ly = idx / SSTR;
        const int gx = x0 - RAD + lx, gy = y0 - RAD + ly;
        float iv = 1e19f, p01 = 0.f, p23 = 0.f;
        if (lx < SW && gx >= 0 && gx < Ww && gy >= 0 && gy < Hh) {
            const int g = gy * Ww + gx;
            iv  = imgb[g] * 255.0f;
            p01 = pack2(labb[g], labb[Hh * Ww + g]);
            p23 = pack2(labb[2 * Hh * Ww + g], labb[3 * Hh * Ww + g]);
        }
        stap[idx] = (f4){iv, p01, p23, 0.f};
    }
    __syncthreads();

    const int tx  = tid & 31;
    const int ty  = (tid >> 5) & 7;   // 0..7 -> which pixel-quad row
    const int grp = tid >> 8;         // 0..1 -> which half of the 14 stencil rows
    const int r0  = 4 * ty;           // top LDS row of this quad's 14-row window

    f4 crec[4];
    float c[4];
#pragma unroll
    for (int p = 0; p < 4; ++p) {
        crec[p] = stap[(r0 + p + RAD) * SSTR + tx + RAD];
        c[p] = crec[p].x;
    }

    f4 num[4];
    f2 den[4];
#pragma unroll
    for (int p = 0; p < 4; ++p) { num[p] = splat4(0.f); den[p] = (f2){0.f, 0.f}; }

    // Row dr (0..13) serves center p (0..3) iff dr in [p, p+10]; group G handles
    // dr = 7G .. 7G+6 (22 active (row,center) pairs each -> balanced). All guards
    // fold at compile time after unrolling.
    auto body = [&](auto GC) {
        constexpr int G = decltype(GC)::value;
#pragma unroll
        for (int d = 0; d < 7; ++d) {
            const int dr = 7 * G + d;
            const int rowoff = (r0 + dr) * SSTR + tx;
#pragma unroll
            for (int i = 0; i < 6; ++i) {
                const f4 rA = stap[rowoff + 2 * i];
                const f4 rB = stap[rowoff + 2 * i + 1];
                const f2 v  = (f2){rA.x, rB.x};
                const f4 a0 = unpack4(rA.y, rA.z);
                const f4 a1 = unpack4(rB.y, rB.z);
#pragma unroll
                for (int p = 0; p < 4; ++p) {
                    if (dr >= p && dr <= p + 10) {      // compile-time guard
                        const f2 base = (f2){(D2[2 * i] + D2[dr - p]) * DSC,
                                             (D2[2 * i + 1] + D2[dr - p]) * DSC};
                        const f2 dd = v - c[p];
                        const f2 a = __builtin_elementwise_fma(dd * KI, dd, base);
                        const float e0 = __builtin_amdgcn_exp2f(a.x);
                        const float e1 = __builtin_amdgcn_exp2f(a.y);
                        den[p] += (f2){e0, e1};
                        num[p] = __builtin_elementwise_fma(splat4(e0), a0, num[p]);
                        num[p] = __builtin_elementwise_fma(splat4(e1), a1, num[p]);
                    }
                }
            }
        }
    };
    if (grp == 0) body(std::integral_constant<int, 0>{});
    else          body(std::integral_constant<int, 1>{});

    // per-class sums of p_f * num and p_f * den over this thread's 4 pixels
    // (partials per row-group; cross-group merge happens in red[][])
    f4 numv = splat4(0.f), denv = splat4(0.f);
#pragma unroll
    for (int p = 0; p < 4; ++p) {
        const f4 pc = unpack4(crec[p].y, crec[p].z);
        const float dn = den[p].x + den[p].y;
        numv = __builtin_elementwise_fma(pc, num[p], numv);
        denv = __builtin_elementwise_fma(pc, splat4(dn), denv);
    }

    float vals[8] = {numv.x, numv.y, numv.z, numv.w, denv.x, denv.y, denv.z, denv.w};

#pragma unroll
    for (int i = 0; i < 8; ++i) {
        float v = vals[i];
#pragma unroll
        for (int off = 32; off > 0; off >>= 1) v += __shfl_down(v, off, 64);
        vals[i] = v;
    }

    const int wave = tid >> 6, lane = tid & 63;   // 8 waves
    if (lane == 0) {
#pragma unroll
        for (int i = 0; i < 8; ++i) red[wave][i] = vals[i];
    }
    __syncthreads();

    if (tid < 8) {
        const int gid = blockIdx.x + GXD * blockIdx.y + GXD * GYD * blockIdx.z;
        float s = 0.f;
#pragma unroll
        for (int w = 0; w < 8; ++w) s += red[w][tid];
        acc[gid * 8 + tid] = s;
    }
}

__global__ void ncut_final(const float* __restrict__ acc, float* __restrict__ out) {
    __shared__ float red[4][64];
    const int t = threadIdx.x;           // 0..255
    const int combo = t & 63;
    const int chunk = t >> 6;            // 0..3
    const int k = combo & 3, b = (combo >> 2) & 7;
    const int part = combo >> 5;         // 0 = num, 1 = den
    float s = 0.f;
    for (int j = chunk; j < PB; j += 4)
        s += acc[(b * PB + j) * 8 + k + 4 * part];
    red[chunk][combo] = s;
    __syncthreads();
    if (t < 64) {
        float v = red[0][t] + red[1][t] + red[2][t] + red[3][t];
        const float den = __shfl(v, (t + 32) & 63, 64);
        float r = (t < 32) ? fabsf(v / den) : 0.f;
#pragma unroll
        for (int off = 32; off > 0; off >>= 1) r += __shfl_down(r, off, 64);
        if (t == 0) out[0] = (float)Kc - r * (1.0f / (float)Bb);
    }
}

extern "C" void kernel_launch(void* const* d_in, const int* in_sizes, int n_in,
                              void* d_out, int out_size, void* d_ws, size_t ws_size,
                              hipStream_t stream) {
    const float* images = (const float*)d_in[0];
    const float* labels = (const float*)d_in[1];
    float* out = (float*)d_out;
    float* acc = (float*)d_ws;  // PB*Bb blocks * 8 partials, fully overwritten each launch

    dim3 grid(GXD, GYD, Bb);    // 7 x 7 x 8
    ncut_main<<<grid, NTHR, 0, stream>>>(images, labels, acc);
    ncut_final<<<1, 256, 0, stream>>>(acc, out);
}

// Round 8
// 83.495 us; speedup vs baseline: 1.1239x; 1.0261x over previous
//
#include <hip/hip_runtime.h>

typedef float f2 __attribute__((ext_vector_type(2)));
typedef float f4 __attribute__((ext_vector_type(4)));
typedef _Float16 h2t __attribute__((ext_vector_type(2)));

constexpr int Hh = 224, Ww = 224, Bb = 8, Kc = 4, RAD = 5;

// 256 threads = 32x8; each thread owns 2 vertically-adjacent pixels -> 32x16 tile.
// SYMMETRY: w_ij == w_ji, so only FORWARD taps (dy>0, or dy==0 && dx>0) are computed;
// per center: S0 = sum_fwd w, S1[k] = sum_fwd w*p_j[k]. Global sums then use
//   num[k] = sum_i p_i[k]*(2*S1_i[k] + p_i[k]),  den[k] = sum_i (p_i[k]*(S0_i+1) + S1_i[k])
// (diagonal w_ii = 1 exactly). Halves every instruction class vs the full window,
// and removes the top halo (staging 26 -> 21 rows).
constexpr int TX = 32;
constexpr int TILEH = 16;
constexpr int NTHR = 256;
constexpr int SW = TX + 2 * RAD;      // 42
constexpr int SH = TILEH + RAD;       // 21 (bottom halo only; forward taps never look up)
constexpr int SSTR = SW + 1;          // 43 (odd; col 42 = pad column)
constexpr int GXD = Ww / TX;          // 7
constexpr int GYD = Hh / TILEH;       // 14
constexpr int PB = GXD * GYD;         // 98 blocks per batch image

constexpr float LOG2E = 1.44269504f;
constexpr float KI = -0.01f * LOG2E;         // intensity coeff (pre-scaled for exp2)
constexpr float DSC = -0.0625f * LOG2E;      // dist coeff     (pre-scaled for exp2)
// column d^2, index = dx+5 (dx in [-5,6]); D2[11]=1e5 -> exp2 underflows to exactly 0,
// masking the dx=+6 slot that the 2-wide pair structure over-covers.
constexpr float D2[12] = {25.f,16.f,9.f,4.f,1.f,0.f,1.f,4.f,9.f,16.f,25.f,1e5f};
// row d^2 for forward dy = 0..5
constexpr float DR2[6] = {0.f,1.f,4.f,9.f,16.f,25.f};

static __device__ inline f4 splat4(float x) { return (f4){x, x, x, x}; }

// f16 labels packed INSIDE f32-typed LDS vectors: loads are ds_read_b128 by
// construction (cannot degrade to ds_read_u16); unpack is pure VALU.
static __device__ inline float pack2(float a, float b) {
    return __builtin_bit_cast(float, __builtin_amdgcn_cvt_pkrtz(a, b));
}
static __device__ inline f4 unpack4(float y, float z) {
    const h2t a = __builtin_bit_cast(h2t, y);
    const h2t b = __builtin_bit_cast(h2t, z);
    return (f4){(float)a.x, (float)a.y, (float)b.x, (float)b.y};
}

__global__ __launch_bounds__(NTHR, 3) void ncut_main(const float* __restrict__ images,
                                                     const float* __restrict__ labels,
                                                     float* __restrict__ acc) {
    // fused tap record: {img*255 (f32), labels k0,k1 (f16x2), labels k2,k3 (f16x2), pad}
    __shared__ f4 stap[SH * SSTR];               // 21*43*16 = 14.4 KB
    __shared__ float red[4][8];

    const int b   = blockIdx.z;
    const int x0  = blockIdx.x * TX;
    const int y0  = blockIdx.y * TILEH;
    const int tid = threadIdx.x;

    const float* imgb = images + (size_t)b * (Hh * Ww);
    const float* labb = labels + (size_t)b * (Kc * Hh * Ww);

    // Stage tile + bottom/side halo (incl. stride-pad column as OOB).
    // OOB: img = 1e19 -> weight underflows to exactly 0; labels = 0.
    for (int idx = tid; idx < SH * SSTR; idx += NTHR) {
        const int lx = idx % SSTR, ly = idx / SSTR;
        const int gx = x0 - RAD + lx, gy = y0 + ly;    // no top halo
        float iv = 1e19f, p01 = 0.f, p23 = 0.f;
        if (lx < SW && gx >= 0 && gx < Ww && gy < Hh) {
            const int g = gy * Ww + gx;
            iv  = imgb[g] * 255.0f;
            p01 = pack2(labb[g], labb[Hh * Ww + g]);
            p23 = pack2(labb[2 * Hh * Ww + g], labb[3 * Hh * Ww + g]);
        }
        stap[idx] = (f4){iv, p01, p23, 0.f};
    }
    __syncthreads();

    const int tx = tid & 31;
    const int ty = tid >> 5;      // 0..7
    const int r0 = 2 * ty;        // tile rows r0, r0+1 (LDS row == tile row)

    const f4 crec0 = stap[r0 * SSTR + tx + RAD];
    const f4 crec1 = stap[(r0 + 1) * SSTR + tx + RAD];
    const float c0 = crec0.x;
    const float c1 = crec1.x;

    f4 s1a = splat4(0.f), s1b = splat4(0.f);     // S1 per center (f4 over classes)
    f2 s0a = (f2){0.f, 0.f}, s0b = (f2){0.f, 0.f};

    // LDS row r0+dr serves center0 with dy=dr (active dr 0..5; dr==0 needs dx>0)
    // and center1 with dy=dr-1 (active dr 1..6; dr==1 needs dx>0). All guards are
    // compile-time after full unroll; dy==0 rows run pairs i>=3 only (dx 1..6, 6 masked).
#pragma unroll
    for (int dr = 0; dr < 7; ++dr) {
        const int rowoff = (r0 + dr) * SSTR + tx;
#pragma unroll
        for (int i = 0; i < 6; ++i) {
            const bool act0 = (dr <= 5) && (dr >= 1 || i >= 3);
            const bool act1 = (dr >= 1) && (dr >= 2 || i >= 3);
            if (act0 || act1) {
                const f4 rA = stap[rowoff + 2 * i];
                const f4 rB = stap[rowoff + 2 * i + 1];
                const f2 v  = (f2){rA.x, rB.x};
                const f4 pa = unpack4(rA.y, rA.z);
                const f4 pb = unpack4(rB.y, rB.z);
                if (act0) {
                    const f2 base = (f2){(D2[2 * i] + DR2[dr]) * DSC,
                                         (D2[2 * i + 1] + DR2[dr]) * DSC};
                    const f2 dd = v - c0;
                    const f2 a = __builtin_elementwise_fma(dd * KI, dd, base);
                    const float e0 = __builtin_amdgcn_exp2f(a.x);
                    const float e1 = __builtin_amdgcn_exp2f(a.y);
                    s0a += (f2){e0, e1};
                    s1a = __builtin_elementwise_fma(splat4(e0), pa, s1a);
                    s1a = __builtin_elementwise_fma(splat4(e1), pb, s1a);
                }
                if (act1) {
                    const f2 base = (f2){(D2[2 * i] + DR2[dr - 1]) * DSC,
                                         (D2[2 * i + 1] + DR2[dr - 1]) * DSC};
                    const f2 dd = v - c1;
                    const f2 a = __builtin_elementwise_fma(dd * KI, dd, base);
                    const float e0 = __builtin_amdgcn_exp2f(a.x);
                    const float e1 = __builtin_amdgcn_exp2f(a.y);
                    s0b += (f2){e0, e1};
                    s1b = __builtin_elementwise_fma(splat4(e0), pa, s1b);
                    s1b = __builtin_elementwise_fma(splat4(e1), pb, s1b);
                }
            }
        }
    }

    // fold symmetric + diagonal contributions for this thread's 2 pixels
    const f4 p0 = unpack4(crec0.y, crec0.z);
    const f4 p1 = unpack4(crec1.y, crec1.z);
    const float S0a = s0a.x + s0a.y;
    const float S0b = s0b.x + s0b.y;

    const f4 numv = p0 * (splat4(2.f) * s1a + p0) + p1 * (splat4(2.f) * s1b + p1);
    const f4 denv = p0 * splat4(S0a + 1.f) + s1a + p1 * splat4(S0b + 1.f) + s1b;

    float vals[8] = {numv.x, numv.y, numv.z, numv.w, denv.x, denv.y, denv.z, denv.w};

#pragma unroll
    for (int i = 0; i < 8; ++i) {
        float vv = vals[i];
#pragma unroll
        for (int off = 32; off > 0; off >>= 1) vv += __shfl_down(vv, off, 64);
        vals[i] = vv;
    }

    const int wave = tid >> 6, lane = tid & 63;   // 4 waves
    if (lane == 0) {
#pragma unroll
        for (int i = 0; i < 8; ++i) red[wave][i] = vals[i];
    }
    __syncthreads();

    if (tid < 8) {
        const int gid = blockIdx.x + GXD * blockIdx.y + GXD * GYD * blockIdx.z;
        acc[gid * 8 + tid] = red[0][tid] + red[1][tid] + red[2][tid] + red[3][tid];
    }
}

__global__ void ncut_final(const float* __restrict__ acc, float* __restrict__ out) {
    __shared__ float red[4][64];
    const int t = threadIdx.x;           // 0..255
    const int combo = t & 63;
    const int chunk = t >> 6;            // 0..3
    const int k = combo & 3, b = (combo >> 2) & 7;
    const int part = combo >> 5;         // 0 = num, 1 = den
    float s = 0.f;
    for (int j = chunk; j < PB; j += 4)
        s += acc[(b * PB + j) * 8 + k + 4 * part];
    red[chunk][combo] = s;
    __syncthreads();
    if (t < 64) {
        float v = red[0][t] + red[1][t] + red[2][t] + red[3][t];
        const float den = __shfl(v, (t + 32) & 63, 64);
        float r = (t < 32) ? fabsf(v / den) : 0.f;
#pragma unroll
        for (int off = 32; off > 0; off >>= 1) r += __shfl_down(r, off, 64);
        if (t == 0) out[0] = (float)Kc - r * (1.0f / (float)Bb);
    }
}

extern "C" void kernel_launch(void* const* d_in, const int* in_sizes, int n_in,
                              void* d_out, int out_size, void* d_ws, size_t ws_size,
                              hipStream_t stream) {
    const float* images = (const float*)d_in[0];
    const float* labels = (const float*)d_in[1];
    float* out = (float*)d_out;
    float* acc = (float*)d_ws;  // PB*Bb blocks * 8 partials, fully overwritten each launch

    dim3 grid(GXD, GYD, Bb);    // 7 x 14 x 8
    ncut_main<<<grid, NTHR, 0, stream>>>(images, labels, acc);
    ncut_final<<<1, 256, 0, stream>>>(acc, out);
}